// Round 21
// baseline (153.779 us; speedup 1.0000x reference)
//
#include <hip/hip_runtime.h>

#define CB 4
#define CH 1440
#define CW 1440
#define NC 32
#define EPSV 1e-3f
#define NBKT (CB * CH)          // 5760 (b,y) buckets
#define BSZ (9 * 2 * 64)        // uint4s per layer of Bfg

typedef __attribute__((ext_vector_type(8))) short bf16x8;
typedef __attribute__((ext_vector_type(16))) float f32x16;

union U16 { uint4 u; bf16x8 v; };

__device__ __forceinline__ unsigned pk2(float a, float b) {
    unsigned ua = __float_as_uint(a), ub = __float_as_uint(b);
    ua += 0x7fffu + ((ua >> 16) & 1u);
    ub += 0x7fffu + ((ub >> 16) & 1u);
    return (ua >> 16) | (ub & 0xffff0000u);
}
__device__ __forceinline__ float bfl(unsigned u) { return __uint_as_float(u << 16); }
__device__ __forceinline__ float bfh(unsigned u) { return __uint_as_float(u & 0xffff0000u); }

// ---------------- kernel 1: key + center-cell clear + (b,y)-bucket histogram -------
__global__ __launch_bounds__(256) void k_hist(
    const int* __restrict__ cb, const int* __restrict__ cy, const int* __restrict__ cx,
    int* __restrict__ idx_map, unsigned* __restrict__ pkey, int* __restrict__ hist,
    int n)
{
    int i = blockIdx.x * blockDim.x + threadIdx.x;
    if (i >= n) return;
    unsigned key = ((unsigned)cb[i] * CH + (unsigned)cy[i]) * CW + (unsigned)cx[i];
    pkey[i] = key;
    idx_map[key] = -1;                       // center-only clear (r13 scheme)
    atomicAdd(&hist[key / CW], 1);           // bucket = b*CH+y
}

// ---------------- kernel 2: one-block exclusive scan + bcnt zero + zero rows -------
__global__ __launch_bounds__(1024) void k_scan(
    const int* __restrict__ hist, int* __restrict__ bstart, int* __restrict__ bcnt,
    unsigned short* __restrict__ z0, unsigned short* __restrict__ z1,
    unsigned short* __restrict__ z2, int n)
{
    __shared__ int ps[1024];
    int tid = threadIdx.x;
    const int PB = 6;                        // 1024*6 = 6144 >= 5760
    int base = tid * PB;
    int loc[PB]; int s = 0;
    #pragma unroll
    for (int j = 0; j < PB; ++j) {
        int idx = base + j;
        int v = (idx < NBKT) ? hist[idx] : 0;
        loc[j] = s; s += v;
    }
    ps[tid] = s;
    __syncthreads();
    for (int off = 1; off < 1024; off <<= 1) {
        int u = (tid >= off) ? ps[tid - off] : 0;
        __syncthreads();
        ps[tid] += u;
        __syncthreads();
    }
    int excl = (tid > 0) ? ps[tid - 1] : 0;
    #pragma unroll
    for (int j = 0; j < PB; ++j)
        if (base + j < NBKT) bstart[base + j] = excl + loc[j];
    for (int i = tid; i < NBKT; i += 1024) bcnt[i] = 0;
    if (tid < 12) {                          // zero row n of the 3 bf16 buffers
        uint4 z = make_uint4(0, 0, 0, 0);
        if (tid < 4)       ((uint4*)(z0 + (size_t)n * 32))[tid] = z;
        else if (tid < 8)  ((uint4*)(z1 + (size_t)n * 32))[tid - 4] = z;
        else               ((uint4*)(z2 + (size_t)n * 32))[tid - 8] = z;
    }
}

// ---------------- kernel 3: rank assignment + map build (orig-index winners) -------
__global__ __launch_bounds__(256) void k_rank(
    const unsigned* __restrict__ pkey, const int* __restrict__ bstart,
    int* __restrict__ bcnt, int* __restrict__ rankof, int* __restrict__ sortidx,
    unsigned* __restrict__ skey, int* __restrict__ idx_map, int n)
{
    int i = blockIdx.x * blockDim.x + threadIdx.x;
    if (i >= n) return;
    unsigned key = pkey[i];
    int bu = key / CW;
    int r = bstart[bu] + atomicAdd(&bcnt[bu], 1);
    rankof[i] = r;
    sortidx[r] = i;
    skey[r] = key;
    atomicMax(&idx_map[key], i);             // numpy last-write-wins by ORIGINAL idx
}

__device__ __forceinline__ int vquery(const int* __restrict__ idx_map,
                                      const unsigned* __restrict__ pkey,
                                      unsigned cell, int n)
{
    int v = idx_map[cell];
    if (v < 0 || v >= n) return -1;
    return (pkey[v] == cell) ? v : -1;
}

// ---------------- kernel 4 (fused): rank-space rulebook + sorted cvt + wcvt --------
__global__ __launch_bounds__(256) void k_prep(
    const unsigned* __restrict__ pkey, const unsigned* __restrict__ skey,
    const int* __restrict__ idx_map, const int* __restrict__ rankof,
    const int* __restrict__ sortidx, int* __restrict__ roff,
    const float* __restrict__ feats, unsigned short* __restrict__ xbf,
    const float* __restrict__ Wk, uint4* __restrict__ Bfg,
    const float* __restrict__ bias, const float* __restrict__ gamma,
    const float* __restrict__ beta, const float* __restrict__ mean,
    const float* __restrict__ var, float* __restrict__ sh_all, int n)
{
    int RB = (n + 255) >> 8;
    int CVT = (n * 2 + 255) >> 8;
    int bx = blockIdx.x;

    if (bx < RB) {                 // ---- rulebook in RANK space ----
        int r = bx * 256 + threadIdx.x;
        if (r >= n) return;
        unsigned key = skey[r];
        unsigned x = key % CW;
        unsigned y = (key / CW) % CH;
        roff[4 * n + r] = rankof[idx_map[key]] * 64;   // own cell: trusted
        #pragma unroll
        for (int k = 0; k < 9; ++k) {
            if (k == 4) continue;
            int dy = k / 3 - 1, dx = k % 3 - 1;
            int ny = (int)y + dy, nx = (int)x + dx;
            int nb = -1;
            if (ny >= 0 && ny < CH && nx >= 0 && nx < CW)
                nb = vquery(idx_map, pkey, key + dy * CW + dx, n);
            roff[k * n + r] = (nb >= 0) ? rankof[nb] * 64 : -1;
        }
    } else if (bx < RB + CVT) {    // ---- feats -> bf16, gathered into SORTED order --
        int t = (bx - RB) * 256 + threadIdx.x;   // t over n*2 half-rows
        if (t < n * 2) {
            int r = t >> 1, half = t & 1;
            const float* src = feats + (size_t)sortidx[r] * 32 + half * 16;
            float4 a0 = *(const float4*)(src);
            float4 a1 = *(const float4*)(src + 4);
            float4 a2 = *(const float4*)(src + 8);
            float4 a3 = *(const float4*)(src + 12);
            uint4 r0, r1;
            r0.x = pk2(a0.x, a0.y); r0.y = pk2(a0.z, a0.w);
            r0.z = pk2(a1.x, a1.y); r0.w = pk2(a1.z, a1.w);
            r1.x = pk2(a2.x, a2.y); r1.y = pk2(a2.z, a2.w);
            r1.z = pk2(a3.x, a3.y); r1.w = pk2(a3.z, a3.w);
            *(uint4*)(xbf + (size_t)r * 32 + half * 16) = r0;
            *(uint4*)(xbf + (size_t)r * 32 + half * 16 + 8) = r1;
        }
    } else {                       // ---- W*sc -> bf16 B-frags + sh ----
        int t = (bx - RB - CVT) * 256 + threadIdx.x;
        if (t >= 6 * 9 * 2 * 64) return;
        int l = t & 63, h = (t >> 6) & 1;
        int rest = t >> 7;
        int k = rest % 9, layer = rest / 9;
        int o = l & 31;
        int lo = layer * 32 + o;
        float scv = gamma[lo] * rsqrtf(var[lo] + EPSV);
        if (k == 0 && h == 0 && l < 32)
            sh_all[lo] = (bias[lo] - mean[lo]) * scv + beta[lo];
        int c0 = h * 16 + 8 * (l >> 5);
        const float* wp = Wk + (size_t)layer * 9216 + k * 1024 + o;   // [c][o]
        uint4 r;
        r.x = pk2(wp[(c0 + 0) * 32] * scv, wp[(c0 + 1) * 32] * scv);
        r.y = pk2(wp[(c0 + 2) * 32] * scv, wp[(c0 + 3) * 32] * scv);
        r.z = pk2(wp[(c0 + 4) * 32] * scv, wp[(c0 + 5) * 32] * scv);
        r.w = pk2(wp[(c0 + 6) * 32] * scv, wp[(c0 + 7) * 32] * scv);
        Bfg[t] = r;
    }
}

// ---------------- kernel 5: gather-K 32x32x16 MFMA conv (rank space, XCD-chunked) --
// NEW vs r19: bijective XCD-chunked block swizzle. Blocks with b%8==c (dispatched
// round-robin to XCD c) cover a CONTIGUOUS tile range, so each XCD's 4MB L2 holds
// its chunk's ~1.6MB of sorted rows + halo -> gathers become L2 hits instead of
// thrashing all 8 L2s across the 12.8MB buffer (explains r16's and r19's nulls).
template<bool ADD_ID, bool F32OUT>
__global__ __launch_bounds__(256, 6) void k_conv(
    const unsigned short* __restrict__ in,   // bf16 [n+1][32] (rank space)
    const unsigned short* __restrict__ idn,  // bf16 [n][32]   (rank space)
    void* __restrict__ outv,                 // bf16 (rank) or f32 (orig)
    const uint4* __restrict__ Bf,
    const float* __restrict__ sh,
    const int* __restrict__ roff, const int* __restrict__ sortidx, int n)
{
    int l = threadIdx.x & 63, wv = threadIdx.x >> 6;
    int q = l & 31, h5 = l >> 5;

    // bijective chunked swizzle (m204 variant): xcd = b&7 gets a contiguous range
    int b = blockIdx.x, Gx = gridDim.x;
    int q8 = Gx >> 3, r8 = Gx & 7;
    int xcd = b & 7, j = b >> 3;
    int base = xcd * q8 + (xcd < r8 ? xcd : r8);
    int swz = base + j;

    int ntile = (n + 31) >> 5;
    int tile = swz * 4 + wv;
    if (tile >= ntile) return;

    const int zoff = n * 64;
    const char* inB = (const char*)in;

    int p0 = tile << 5;
    int pr = p0 + q;
    bool rowok = pr < n;
    int prc = rowok ? pr : n - 1;

    int rk[9];
    #pragma unroll
    for (int k = 0; k < 9; ++k) rk[k] = roff[(size_t)k * n + prc];

    f32x16 acc = {0.f,0.f,0.f,0.f,0.f,0.f,0.f,0.f,0.f,0.f,0.f,0.f,0.f,0.f,0.f,0.f};

    #pragma unroll
    for (int g = 0; g < 3; ++g) {
        bool act[3];
        U16 a0[3], a1[3];
        #pragma unroll
        for (int j2 = 0; j2 < 3; ++j2) {
            int k = g * 3 + j2;
            act[j2] = __any(rk[k] >= 0);
            if (act[j2]) {
                int off = (rowok && rk[k] >= 0) ? rk[k] : zoff;
                const char* ap = inB + off + h5 * 16;
                a0[j2].u = *(const uint4*)(ap);
                a1[j2].u = *(const uint4*)(ap + 32);
            }
        }
        #pragma unroll
        for (int j2 = 0; j2 < 3; ++j2) {
            int k = g * 3 + j2;
            if (act[j2]) {
                U16 b0, b1;
                b0.u = Bf[(k * 2 + 0) * 64 + l];
                b1.u = Bf[(k * 2 + 1) * 64 + l];
                acc = __builtin_amdgcn_mfma_f32_32x32x16_bf16(b0.v, a0[j2].v, acc, 0, 0, 0);
                acc = __builtin_amdgcn_mfma_f32_32x32x16_bf16(b1.v, a1[j2].v, acc, 0, 0, 0);
            }
        }
    }

    if (rowok) {
        int orow = F32OUT ? sortidx[pr] : pr;
        #pragma unroll
        for (int g = 0; g < 4; ++g) {
            int ch = g * 8 + 4 * h5;
            float4 s4 = *(const float4*)(sh + ch);
            float y0 = acc[g * 4 + 0] + s4.x;
            float y1 = acc[g * 4 + 1] + s4.y;
            float y2 = acc[g * 4 + 2] + s4.z;
            float y3 = acc[g * 4 + 3] + s4.w;
            if (ADD_ID) {
                uint2 iv = *(const uint2*)(idn + (size_t)pr * 32 + ch);
                y0 += bfl(iv.x); y1 += bfh(iv.x);
                y2 += bfl(iv.y); y3 += bfh(iv.y);
            }
            y0 = fmaxf(y0, 0.f); y1 = fmaxf(y1, 0.f);
            y2 = fmaxf(y2, 0.f); y3 = fmaxf(y3, 0.f);
            if (F32OUT) {
                *(float4*)((float*)outv + (size_t)orow * 32 + ch) =
                    make_float4(y0, y1, y2, y3);
            } else {
                uint2 r;
                r.x = pk2(y0, y1); r.y = pk2(y2, y3);
                *(uint2*)((unsigned short*)outv + (size_t)pr * 32 + ch) = r;
            }
        }
    }
}

extern "C" void kernel_launch(void* const* d_in, const int* in_sizes, int n_in,
                              void* d_out, int out_size, void* d_ws, size_t ws_size,
                              hipStream_t stream)
{
    const float* feats = (const float*)d_in[0];
    const float* Wk    = (const float*)d_in[1];  // [3][2][9][32][32]
    const float* bias  = (const float*)d_in[2];
    const float* gamma = (const float*)d_in[3];
    const float* beta  = (const float*)d_in[4];
    const float* mean  = (const float*)d_in[5];
    const float* var   = (const float*)d_in[6];
    const int* cb = (const int*)d_in[7];
    const int* cy = (const int*)d_in[8];
    const int* cx = (const int*)d_in[9];
    float* out = (float*)d_out;
    int n = in_sizes[0] / NC;

    char* ws = (char*)d_ws;
    int*            idx_map = (int*)(ws + 0);                   // 33,177,600 B
    unsigned*       pkey    = (unsigned*)(ws + 33177600);       //    800,000 B
    int*            roff    = (int*)(ws + 33977600);            //  7,200,000 B
    uint4*          Bfg     = (uint4*)(ws + 41177600);          //    110,592 B
    float*          sh_all  = (float*)(ws + 41288192);          //        768 B
    int*            hist    = (int*)(ws + 41288960);            //     23,040 B
    int*            bcnt    = (int*)(ws + 41312000);            //     23,040 B
    int*            bstart  = (int*)(ws + 41335040);            //     23,040 B
    int*            rankof  = (int*)(ws + 41358080);            //    800,000 B
    int*            sortidx = (int*)(ws + 42158080);            //    800,000 B
    unsigned*       skey    = (unsigned*)(ws + 42958080);       //    800,000 B
    unsigned short* xbf     = (unsigned short*)(ws + 43758080); // 12,800,064 B
    unsigned short* tmpbf   = (unsigned short*)(ws + 56558144); // 12,800,064 B
    unsigned short* hb      = (unsigned short*)(ws + 69358208); // 12,800,064 B

    (void)hipMemsetAsync(hist, 0, 23040, stream);

    int RB  = (n + 255) / 256;
    int CVT = (n * 2 + 255) / 256;
    k_hist<<<RB, 256, 0, stream>>>(cb, cy, cx, idx_map, pkey, hist, n);
    k_scan<<<1, 1024, 0, stream>>>(hist, bstart, bcnt, xbf, tmpbf, hb, n);
    k_rank<<<RB, 256, 0, stream>>>(pkey, bstart, bcnt, rankof, sortidx, skey,
        idx_map, n);
    k_prep<<<RB + CVT + 27, 256, 0, stream>>>(
        pkey, skey, idx_map, rankof, sortidx, roff, feats, xbf, Wk, Bfg,
        bias, gamma, beta, mean, var, sh_all, n);

    const int ntile = (n + 31) / 32;
    const int G = (ntile + 3) / 4;   // one tile per wave, single pass

    k_conv<false, false><<<G, 256, 0, stream>>>(xbf, nullptr, tmpbf,
        Bfg + 0 * BSZ, sh_all + 0,   roff, sortidx, n);
    k_conv<true,  false><<<G, 256, 0, stream>>>(tmpbf, xbf, hb,
        Bfg + 1 * BSZ, sh_all + 32,  roff, sortidx, n);
    k_conv<false, false><<<G, 256, 0, stream>>>(hb, nullptr, tmpbf,
        Bfg + 2 * BSZ, sh_all + 64,  roff, sortidx, n);
    k_conv<true,  false><<<G, 256, 0, stream>>>(tmpbf, hb, xbf,
        Bfg + 3 * BSZ, sh_all + 96,  roff, sortidx, n);
    k_conv<false, false><<<G, 256, 0, stream>>>(xbf, nullptr, tmpbf,
        Bfg + 4 * BSZ, sh_all + 128, roff, sortidx, n);
    k_conv<true,  true ><<<G, 256, 0, stream>>>(tmpbf, xbf, out,
        Bfg + 5 * BSZ, sh_all + 160, roff, sortidx, n);
}